// Round 4
// baseline (283.184 us; speedup 1.0000x reference)
//
// AttentionModel: fused QKV projection + causal softmax attention, MI355X/gfx950.
// Round 4: pure-gload GEMM core (m97 shape). Diagnosis R1-R3: register-path
// global loads (fp32 A / preH prefetch) serialize on vmcnt and cap all GEMMs
// at ~330 TF regardless of buffering strategy. Fix: ALL global->LDS staging is
// fire-and-forget global_load_lds (width 16); single As+Bs (32 KB LDS), two
// barriers per K-iter; latency hidden by cross-block overlap (4-5 blocks/CU).
// fp32 inputs are pre-converted to f16 by k_cvtin (streamed into the P region,
// which is dead until k_scores).
//  - XCD swizzles kept from R3 (proj FETCH 198->54 MB, verified).
// ws layout (bytes): P/Xf16 0..64M | Qb 64M | Kb 80M | Vb 96M | Vt 112M | Wf16 128M

#include <hip/hip_runtime.h>
#include <stdint.h>
#include <stddef.h>
#include <math.h>

typedef _Float16 half8 __attribute__((ext_vector_type(8)));
typedef float f32x4 __attribute__((ext_vector_type(4)));

#define SCALE_QK 0.04419417382415922f  // 1/sqrt(512)

__device__ __forceinline__ void gload16(const void* g, void* lds) {
  __builtin_amdgcn_global_load_lds(
      (const __attribute__((address_space(1))) void*)g,
      (__attribute__((address_space(3))) void*)lds,
      16, 0, 0);
}

// m97-style K-loop: C[128x128] = A[128xK] * B^T (B stored [N][K]), f16 MFMA.
// Both operands staged via global_load_lds into single 16 KB buffers.
// LDS layout contract: element (row r, 8-group g) at halfword r*64 + (g^(r&7))*8.
__device__ __forceinline__ void run_kloop(const _Float16* A, const _Float16* B,
                                          int lda, int ldb, int kIters,
                                          _Float16* As, _Float16* Bs,
                                          f32x4 (&acc)[4][4])
{
  const int tid  = threadIdx.x;
  const int lane = tid & 63;
  const int w    = tid >> 6;
  const int wm   = w >> 1, wn = w & 1;
  const int srow = tid >> 3;          // staging row within 32-row chunk
  const int sg   = tid & 7;           // staging slot
  const int swz  = sg ^ (srow & 7);   // fetch swizzled global group into slot sg
  const int fr   = lane & 15;         // fragment m/n within 16
  const int fq   = lane >> 4;         // k-quad
  const int fx   = lane & 7;          // read-side swizzle

  auto stage = [&](int it) {
    const int k0 = it * 64;
    #pragma unroll
    for (int i = 0; i < 4; ++i) {
      gload16(A + (size_t)(i*32 + srow) * lda + (k0 + swz*8), As + i*2048 + w*512);
      gload16(B + (size_t)(i*32 + srow) * ldb + (k0 + swz*8), Bs + i*2048 + w*512);
    }
  };
  auto compute = [&]() {
    #pragma unroll
    for (int ks = 0; ks < 2; ++ks) {
      half8 av[4], bv[4];
      const int slot = (ks*4 + fq) ^ fx;
      #pragma unroll
      for (int i = 0; i < 4; ++i) {
        av[i] = *(const half8*)(As + (wm*64 + i*16 + fr)*64 + slot*8);
        bv[i] = *(const half8*)(Bs + (wn*64 + i*16 + fr)*64 + slot*8);
      }
      #pragma unroll
      for (int i = 0; i < 4; ++i) {
        #pragma unroll
        for (int j = 0; j < 4; ++j)
          acc[i][j] = __builtin_amdgcn_mfma_f32_16x16x32_f16(av[i], bv[j], acc[i][j], 0, 0, 0);
      }
    }
  };

  stage(0);
  __syncthreads();                 // drain gloads
  for (int it = 0; ; ) {
    compute();
    if (++it >= kIters) break;
    __syncthreads();               // LDS readers done
    stage(it);
    __syncthreads();               // drain gloads
  }
}

// ---- weights fp32 -> f16 (3 x 512x512 concatenated) ----
__global__ __launch_bounds__(256) void k_cvtw(const float* __restrict__ Wq,
                                              const float* __restrict__ Wk,
                                              const float* __restrict__ Wv,
                                              _Float16* __restrict__ Wb)
{
  const int t = blockIdx.x * 256 + threadIdx.x;
  const int base = t * 8;                 // 786432 total elems
  const int z = base >> 18;               // 262144 per matrix
  const int off = base & 262143;
  const float* src = (z == 0) ? Wq : ((z == 1) ? Wk : Wv);
  f32x4 a = *(const f32x4*)(src + off);
  f32x4 b = *(const f32x4*)(src + off + 4);
  half8 h;
  h[0]=(_Float16)a[0]; h[1]=(_Float16)a[1]; h[2]=(_Float16)a[2]; h[3]=(_Float16)a[3];
  h[4]=(_Float16)b[0]; h[5]=(_Float16)b[1]; h[6]=(_Float16)b[2]; h[7]=(_Float16)b[3];
  *(half8*)(Wb + base) = h;
}

// ---- inputs q,k,v fp32 -> f16, concatenated into X (3 x 16384x512) ----
__global__ __launch_bounds__(256) void k_cvtin(const float* __restrict__ q,
                                               const float* __restrict__ k,
                                               const float* __restrict__ v,
                                               _Float16* __restrict__ X)
{
  const size_t t = (size_t)blockIdx.x * 256 + threadIdx.x;
  const size_t base = t * 8;              // 25165824 total elems
  const int z = (int)(base >> 23);        // 8388608 per tensor
  const size_t off = base & 8388607;
  const float* src = (z == 0) ? q : ((z == 1) ? k : v);
  f32x4 a = *(const f32x4*)(src + off);
  f32x4 b = *(const f32x4*)(src + off + 4);
  half8 h;
  h[0]=(_Float16)a[0]; h[1]=(_Float16)a[1]; h[2]=(_Float16)a[2]; h[3]=(_Float16)a[3];
  h[4]=(_Float16)b[0]; h[5]=(_Float16)b[1]; h[6]=(_Float16)b[2]; h[7]=(_Float16)b[3];
  *(half8*)(X + base) = h;
}

// ---- projections: X[16384x512](f16) @ W^T + bias -> f16 ----
// 1D grid 1536: xcd = bid%8; i = bid/8; panel p = xcd*48 + i/4; nt = i%4;
// z = p/128, mt = p%128. All 4 nt-siblings of a panel share an XCD's L2.
__global__ __launch_bounds__(256) void k_proj(const _Float16* __restrict__ X,
                                              const _Float16* __restrict__ Wb,
                                              const float* __restrict__ bq,
                                              const float* __restrict__ bk,
                                              const float* __restrict__ bv,
                                              _Float16* __restrict__ Qb,
                                              _Float16* __restrict__ Kb,
                                              _Float16* __restrict__ Vb)
{
  __shared__ __align__(16) _Float16 As[128*64];
  __shared__ __align__(16) _Float16 Bs[128*64];
  const int bid = blockIdx.x;
  const int xcd = bid & 7, i = bid >> 3;
  const int p = xcd * 48 + (i >> 2);
  const int nt = i & 3;
  const int z = p >> 7, mt = p & 127;

  const _Float16* A  = X + (size_t)z * 8388608;
  const float* bia   = (z == 0) ? bq : (z == 1) ? bk : bv;
  const _Float16* B  = Wb + (size_t)z * 512 * 512;
  _Float16* C        = (z == 0) ? Qb : (z == 1) ? Kb : Vb;

  f32x4 acc[4][4] = {};
  run_kloop(A + (size_t)mt*128*512, B + (size_t)nt*128*512, 512, 512, 8, As, Bs, acc);

  const int lane = threadIdx.x & 63, w = threadIdx.x >> 6;
  const int wm = w >> 1, wn = w & 1;
  const int fr = lane & 15, fq = lane >> 4;   // C/D: col=lane&15, row=(lane>>4)*4+reg
  #pragma unroll
  for (int j = 0; j < 4; ++j) {
    const int col = nt*128 + wn*64 + j*16 + fr;
    const float bval = bia[col];
    #pragma unroll
    for (int i2 = 0; i2 < 4; ++i2) {
      const int row = mt*128 + wm*64 + i2*16 + fq*4;
      #pragma unroll
      for (int r = 0; r < 4; ++r)
        C[(size_t)(row + r) * 512 + col] = (_Float16)(acc[i2][j][r] + bval);
    }
  }
}

// ---- V[s][d] -> Vt[d][s] per batch ----
__global__ __launch_bounds__(256) void k_trans(const _Float16* __restrict__ Vb,
                                               _Float16* __restrict__ Vt)
{
  __shared__ __align__(16) _Float16 t[64][72];  // pad 8 to spread banks
  const int st = blockIdx.x, dt = blockIdx.y, b = blockIdx.z;
  const int r = threadIdx.x >> 2, g = threadIdx.x & 3;
  const _Float16* src = Vb + ((size_t)b*2048 + st*64 + r)*512 + dt*64 + g*16;
  half8 v0 = *(const half8*)src;
  half8 v1 = *(const half8*)(src + 8);
  *(half8*)&t[r][g*16]     = v0;
  *(half8*)&t[r][g*16 + 8] = v1;
  __syncthreads();
  half8 o0, o1;
  #pragma unroll
  for (int i2 = 0; i2 < 8; ++i2) o0[i2] = t[g*16 + i2][r];
  #pragma unroll
  for (int i2 = 0; i2 < 8; ++i2) o1[i2] = t[g*16 + 8 + i2][r];
  _Float16* dst = Vt + ((size_t)b*512 + dt*64 + r)*2048 + st*64 + g*16;
  *(half8*)dst       = o0;
  *(half8*)(dst + 8) = o1;
}

// ---- scores: S = Q K^T * scale ----
// 1D grid 1088: b = bid%8 (-> XCD b); t = bid/8 in [0,136) triangular-decoded
// to (qt,kt), kt<=qt. Per-batch Q+K (4MB) is L2-resident on its XCD.
__global__ __launch_bounds__(256) void k_scores(const _Float16* __restrict__ Qb,
                                                const _Float16* __restrict__ Kb,
                                                _Float16* __restrict__ P)
{
  const int bid = blockIdx.x;
  const int b = bid & 7;
  const int t = bid >> 3;
  int qt = (int)((sqrtf(8.0f * (float)t + 1.0f) - 1.0f) * 0.5f);
  int base = (qt * (qt + 1)) >> 1;
  if (t < base)                { --qt; base = (qt * (qt + 1)) >> 1; }
  else if (t >= base + qt + 1) { ++qt; base = (qt * (qt + 1)) >> 1; }
  const int kt = t - base;

  __shared__ __align__(16) _Float16 As[128*64];
  __shared__ __align__(16) _Float16 Bs[128*64];
  f32x4 acc[4][4] = {};
  run_kloop(Qb + ((size_t)b*2048 + qt*128)*512,
            Kb + ((size_t)b*2048 + kt*128)*512,
            512, 512, 8, As, Bs, acc);
  const int lane = threadIdx.x & 63, w = threadIdx.x >> 6;
  const int wm = w >> 1, wn = w & 1;
  const int fr = lane & 15, fq = lane >> 4;
  #pragma unroll
  for (int i = 0; i < 4; ++i) {
    const int row = qt*128 + wm*64 + i*16 + fq*4;
    #pragma unroll
    for (int j = 0; j < 4; ++j) {
      const int col = kt*128 + wn*64 + j*16 + fr;
      #pragma unroll
      for (int r = 0; r < 4; ++r)
        P[((size_t)b*2048 + row + r) * 2048 + col] = (_Float16)(acc[i][j][r] * SCALE_QK);
    }
  }
}

// ---- in-place causal row softmax; one wave per row; online max/sum ----
__global__ __launch_bounds__(256) void k_softmax(_Float16* __restrict__ P)
{
  const int lane = threadIdx.x & 63;
  const int row  = blockIdx.x * 4 + (threadIdx.x >> 6);  // 0..16383 (= b*2048+q)
  const int qIdx = row & 2047;
  _Float16* p = P + (size_t)row * 2048;
  const int L    = qIdx + 1;                    // causal length
  const int Lpad = ((qIdx >> 7) + 1) * 128;     // PV kernel reads up to here

  float m = -1e30f, s = 0.f;
  for (int i0 = lane * 8; i0 < L; i0 += 512) {
    float xv[8];
    if (i0 + 8 <= L) {
      half8 x = *(const half8*)(p + i0);
      #pragma unroll
      for (int j = 0; j < 8; ++j) xv[j] = (float)x[j];
    } else {
      #pragma unroll
      for (int j = 0; j < 8; ++j) xv[j] = (i0 + j < L) ? (float)p[i0 + j] : -1e30f;
    }
    float cm = xv[0];
    #pragma unroll
    for (int j = 1; j < 8; ++j) cm = fmaxf(cm, xv[j]);
    const float mn = fmaxf(m, cm);
    float cs = 0.f;
    #pragma unroll
    for (int j = 0; j < 8; ++j) cs += __expf(xv[j] - mn);  // exp(-huge)=0 for pads
    s = s * __expf(m - mn) + cs;
    m = mn;
  }
  #pragma unroll
  for (int d = 1; d < 64; d <<= 1) {
    const float mo = __shfl_xor(m, d, 64);
    const float so = __shfl_xor(s, d, 64);
    const float mn = fmaxf(m, mo);
    s = s * __expf(m - mn) + so * __expf(mo - mn);
    m = mn;
  }
  const float inv = 1.0f / s;

  for (int i0 = lane * 8; i0 < Lpad; i0 += 512) {
    half8 o;
    if (i0 + 8 <= L) {
      half8 x = *(const half8*)(p + i0);
      #pragma unroll
      for (int j = 0; j < 8; ++j) o[j] = (_Float16)(__expf((float)x[j] - m) * inv);
    } else {
      #pragma unroll
      for (int j = 0; j < 8; ++j) {
        const int idx = i0 + j;
        o[j] = (idx < L) ? (_Float16)(__expf((float)p[idx] - m) * inv) : (_Float16)0.f;
      }
    }
    *(half8*)(p + i0) = o;
  }
}

// ---- out = P @ V  (B-operand = Vt[d][s]), causal K-extent ----
// 1D grid 512: b = bid%8 (-> XCD b); r = bid/8 in [0,64): qi=r/4 interleaved
// long/short for balance, dt=r%4 (dt-siblings adjacent -> P rows L2-hot).
__global__ __launch_bounds__(256) void k_pv(const _Float16* __restrict__ P,
                                            const _Float16* __restrict__ Vt,
                                            float* __restrict__ Out)
{
  const int bid = blockIdx.x;
  const int b = bid & 7;
  const int r0 = bid >> 3;
  const int qi = r0 >> 2, dt = r0 & 3;
  const int qt = (qi & 1) ? (15 - (qi >> 1)) : (qi >> 1);

  __shared__ __align__(16) _Float16 As[128*64];
  __shared__ __align__(16) _Float16 Bs[128*64];
  f32x4 acc[4][4] = {};
  run_kloop(P  + ((size_t)b*2048 + qt*128)*2048,
            Vt + ((size_t)b*512  + dt*128)*2048,
            2048, 2048, (qt + 1) * 2, As, Bs, acc);
  const int lane = threadIdx.x & 63, w = threadIdx.x >> 6;
  const int wm = w >> 1, wn = w & 1;
  const int fr = lane & 15, fq = lane >> 4;
  #pragma unroll
  for (int i = 0; i < 4; ++i) {
    const int row = qt*128 + wm*64 + i*16 + fq*4;
    #pragma unroll
    for (int j = 0; j < 4; ++j) {
      const int col = dt*128 + wn*64 + j*16 + fr;
      #pragma unroll
      for (int r = 0; r < 4; ++r)
        Out[((size_t)b*2048 + row + r) * 512 + col] = acc[i][j][r];
    }
  }
}

extern "C" void kernel_launch(void* const* d_in, const int* in_sizes, int n_in,
                              void* d_out, int out_size, void* d_ws, size_t ws_size,
                              hipStream_t stream) {
  (void)in_sizes; (void)n_in; (void)out_size;
  const float* q  = (const float*)d_in[0];
  const float* k  = (const float*)d_in[1];
  const float* v  = (const float*)d_in[2];
  // d_in[3] = causal mask: always tril per setup; implemented structurally.
  const float* Wq = (const float*)d_in[4];
  const float* bq = (const float*)d_in[5];
  const float* Wk = (const float*)d_in[6];
  const float* bk = (const float*)d_in[7];
  const float* Wv = (const float*)d_in[8];
  const float* bv = (const float*)d_in[9];

  const size_t OFF_P  = 0;                 // X (f16 inputs) lives here pre-scores
  const size_t OFF_Q  = (size_t)64 << 20;
  const size_t OFF_K  = (size_t)80 << 20;
  const size_t OFF_V  = (size_t)96 << 20;
  const size_t OFF_VT = (size_t)112 << 20;
  const size_t OFF_W  = (size_t)128 << 20;
  const size_t NEEDED = OFF_W + (size_t)3 * 512 * 512 * sizeof(_Float16);
  if (ws_size < NEEDED) return;  // diagnostic: poison-level absmax => ws too small

  char* ws = (char*)d_ws;
  _Float16* P  = (_Float16*)(ws + OFF_P);
  _Float16* X  = (_Float16*)(ws + OFF_P);  // alias: dead once k_scores writes P
  _Float16* Qb = (_Float16*)(ws + OFF_Q);
  _Float16* Kb = (_Float16*)(ws + OFF_K);
  _Float16* Vb = (_Float16*)(ws + OFF_V);
  _Float16* Vt = (_Float16*)(ws + OFF_VT);
  _Float16* Wb = (_Float16*)(ws + OFF_W);
  float* Out = (float*)d_out;

  k_cvtw   <<<dim3(384),      dim3(256), 0, stream>>>(Wq, Wk, Wv, Wb);
  k_cvtin  <<<dim3(12288),    dim3(256), 0, stream>>>(q, k, v, X);
  k_proj   <<<dim3(1536),     dim3(256), 0, stream>>>(X, Wb, bq, bk, bv, Qb, Kb, Vb);
  k_trans  <<<dim3(32, 8, 8), dim3(256), 0, stream>>>(Vb, Vt);
  k_scores <<<dim3(1088),     dim3(256), 0, stream>>>(Qb, Kb, P);
  k_softmax<<<dim3(4096),     dim3(256), 0, stream>>>(P);
  k_pv     <<<dim3(512),      dim3(256), 0, stream>>>(P, Vt, Out);
}